// Round 1
// baseline (168.397 us; speedup 1.0000x reference)
//
#include <hip/hip_runtime.h>

// Problem dims fixed by setup_inputs(): B=16, C=1, H=W=2048, fp32.
#define HDIM 2048
#define WDIM 2048
#define WV   (WDIM / 4)   // float4 vectors per row = 512 (power of 2)

// out[w] = kx0 * (w>=1   ? x[w-1]  : 0) + kx1 * (w<=W-2 ? x[w]   : 0)
//        + ky0 * (h>=1   ? y[h-1,w]: 0) + ky1 * (h<=H-2 ? y[h,w] : 0)
__global__ __launch_bounds__(256) void grad_sum_kernel(
    const float* __restrict__ x, const float* __restrict__ y,
    const float* __restrict__ kx, const float* __restrict__ ky,
    float* __restrict__ out, int nvec)
{
    const float kx0 = kx[0], kx1 = kx[1];
    const float ky0 = ky[0], ky1 = ky[1];

    const int stride = gridDim.x * blockDim.x;
    for (int idx = blockIdx.x * blockDim.x + threadIdx.x; idx < nvec; idx += stride) {
        const int wv = idx & (WV - 1);              // vector index within row
        const int h  = (idx >> 9) & (HDIM - 1);     // row within image (WV=512=2^9)
        const long long base = (long long)idx << 2; // flat element index (layout [b][h][w])

        const float4 xv = *reinterpret_cast<const float4*>(x + base);
        const float4 yv = *reinterpret_cast<const float4*>(y + base);

        // x[w0-1]: gated to 0 at row start (w0 == 0)
        float xm1 = 0.0f;
        if (wv > 0) xm1 = x[base - 1];

        // y[h-1, w0..w0+3]: gated to 0 on first row
        float4 ym1 = make_float4(0.0f, 0.0f, 0.0f, 0.0f);
        if (h > 0) ym1 = *reinterpret_cast<const float4*>(y + base - WDIM);

        const bool lastH = (h == HDIM - 1);
        const float yc0 = lastH ? 0.0f : yv.x;
        const float yc1 = lastH ? 0.0f : yv.y;
        const float yc2 = lastH ? 0.0f : yv.z;
        const float yc3 = lastH ? 0.0f : yv.w;

        // diff_x "a" term: x[w-1] (j=0 -> xm1, j>0 -> shifted xv)
        const float a0 = xm1;
        const float a1 = xv.x;
        const float a2 = xv.y;
        const float a3 = xv.z;
        // diff_x "b" term: x[w] gated off at w == W-1 (only j=3 of last vector)
        const float b0 = xv.x;
        const float b1 = xv.y;
        const float b2 = xv.z;
        const float b3 = (wv == WV - 1) ? 0.0f : xv.w;

        float4 o;
        o.x = kx0 * a0 + kx1 * b0 + ky0 * ym1.x + ky1 * yc0;
        o.y = kx0 * a1 + kx1 * b1 + ky0 * ym1.y + ky1 * yc1;
        o.z = kx0 * a2 + kx1 * b2 + ky0 * ym1.z + ky1 * yc2;
        o.w = kx0 * a3 + kx1 * b3 + ky0 * ym1.w + ky1 * yc3;

        *reinterpret_cast<float4*>(out + base) = o;
    }
}

extern "C" void kernel_launch(void* const* d_in, const int* in_sizes, int n_in,
                              void* d_out, int out_size, void* d_ws, size_t ws_size,
                              hipStream_t stream) {
    const float* x  = (const float*)d_in[0];
    const float* y  = (const float*)d_in[1];
    const float* kx = (const float*)d_in[2];
    const float* ky = (const float*)d_in[3];
    float* out = (float*)d_out;

    const int nvec  = out_size / 4;          // float4 vectors
    const int block = 256;
    int grid = (nvec + block - 1) / block;
    if (grid > 4096) grid = 4096;            // grid-stride the rest

    grad_sum_kernel<<<grid, block, 0, stream>>>(x, y, kx, ky, out, nvec);
}

// Round 3
// 144.002 us; speedup vs baseline: 1.1694x; 1.1694x over previous
//
#include <hip/hip_runtime.h>

// Problem dims fixed by setup_inputs(): B=16, C=1, H=W=2048, fp32.
#define HDIM 2048
#define WDIM 2048
#define WV   512      // float4 vectors per row
#define ROWS 4        // rows per block tile
#define TPB  256      // threads per block

typedef float f4 __attribute__((ext_vector_type(4)));   // native vec4 (nontemporal-ok)

// out[h][w] = kx0*(w>=1 ? x[h][w-1] : 0) + kx1*(w<=W-2 ? x[h][w] : 0)
//           + ky0*(h>=1 ? y[h-1][w] : 0) + ky1*(h<=H-2 ? y[h][w] : 0)
//
// Block tile: 4 full rows (ROWS x WDIM). 256 threads cover one row in two
// 256-vec4 chunks (A: cols [0,256), B: cols [256,512)). y[h-1] for rows 1..3
// is carried in registers from the previous row iteration; only the tile's
// first row loads the row above (block-uniform branch). x[w-1] comes from a
// dword-aligned shifted float4 load (same cachelines as x[w], L1 hit).
__global__ __launch_bounds__(TPB) void grad_sum_kernel(
    const float* __restrict__ x, const float* __restrict__ y,
    const float* __restrict__ kxp, const float* __restrict__ kyp,
    float* __restrict__ out)
{
    const float kx0 = kxp[0], kx1 = kxp[1];
    const float ky0 = kyp[0], ky1 = kyp[1];

    const int t    = threadIdx.x;
    const int bid  = blockIdx.x;
    const int tile = bid & 511;          // 512 tiles (of 4 rows) per image
    const int img  = bid >> 9;
    const int r0   = tile * ROWS;

    const long long ibase = (long long)img * (HDIM * WDIM) + (long long)r0 * WDIM;
    const int c0 = t;                    // chunk A vec4 column
    const int c1 = t + TPB;              // chunk B vec4 column

    // previous-row y (zero for the image's first row) — block-uniform branch
    f4 ymA = (f4){0.f, 0.f, 0.f, 0.f};
    f4 ymB = (f4){0.f, 0.f, 0.f, 0.f};
    if (r0 != 0) {
        ymA = *reinterpret_cast<const f4*>(y + ibase - WDIM + c0 * 4);
        ymB = *reinterpret_cast<const f4*>(y + ibase - WDIM + c1 * 4);
    }

    #pragma unroll
    for (int r = 0; r < ROWS; ++r) {
        const long long rb = ibase + (long long)r * WDIM;
        const int h = r0 + r;

        // ---- loads (6 independent float4s) ----
        const f4 xvA = *reinterpret_cast<const f4*>(x + rb + c0 * 4);
        const f4 xvB = *reinterpret_cast<const f4*>(x + rb + c1 * 4);
        // shifted-by-one x vector: elements [c*4-1 .. c*4+2] (dword-aligned)
        f4 xsA = *reinterpret_cast<const f4*>(x + rb + (c0 ? c0 * 4 - 1 : 0));
        const f4 xsB = *reinterpret_cast<const f4*>(x + rb + c1 * 4 - 1);
        const f4 yvA = *reinterpret_cast<const f4*>(y + rb + c0 * 4);
        const f4 yvB = *reinterpret_cast<const f4*>(y + rb + c1 * 4);

        // w==0 boundary: a-vector is (0, x[0], x[1], x[2])
        if (c0 == 0) xsA = (f4){0.f, xvA.x, xvA.y, xvA.z};

        // h==H-1 boundary: ky1 term gated (block-uniform)
        const bool lastH = (h == HDIM - 1);
        const f4 zero = (f4){0.f, 0.f, 0.f, 0.f};
        const f4 ycA = lastH ? zero : yvA;
        const f4 ycB = lastH ? zero : yvB;

        // w==W-1 boundary: kx1 term gated (only last element of chunk B)
        const float bB3 = (c1 == WV - 1) ? 0.f : xvB.w;

        f4 oA, oB;
        oA.x = kx0 * xsA.x + kx1 * xvA.x + ky0 * ymA.x + ky1 * ycA.x;
        oA.y = kx0 * xsA.y + kx1 * xvA.y + ky0 * ymA.y + ky1 * ycA.y;
        oA.z = kx0 * xsA.z + kx1 * xvA.z + ky0 * ymA.z + ky1 * ycA.z;
        oA.w = kx0 * xsA.w + kx1 * xvA.w + ky0 * ymA.w + ky1 * ycA.w;

        oB.x = kx0 * xsB.x + kx1 * xvB.x + ky0 * ymB.x + ky1 * ycB.x;
        oB.y = kx0 * xsB.y + kx1 * xvB.y + ky0 * ymB.y + ky1 * ycB.y;
        oB.z = kx0 * xsB.z + kx1 * xvB.z + ky0 * ymB.z + ky1 * ycB.z;
        oB.w = kx0 * xsB.w + kx1 * bB3   + ky0 * ymB.w + ky1 * ycB.w;

        __builtin_nontemporal_store(oA, reinterpret_cast<f4*>(out + rb + c0 * 4));
        __builtin_nontemporal_store(oB, reinterpret_cast<f4*>(out + rb + c1 * 4));

        // register-carry y row for next iteration's ky0 term
        ymA = yvA;
        ymB = yvB;
    }
}

extern "C" void kernel_launch(void* const* d_in, const int* in_sizes, int n_in,
                              void* d_out, int out_size, void* d_ws, size_t ws_size,
                              hipStream_t stream) {
    const float* x  = (const float*)d_in[0];
    const float* y  = (const float*)d_in[1];
    const float* kx = (const float*)d_in[2];
    const float* ky = (const float*)d_in[3];
    float* out = (float*)d_out;

    // 16 images x (2048/ROWS) row-tiles = 8192 blocks
    const int grid = 16 * (HDIM / ROWS);
    grad_sum_kernel<<<grid, TPB, 0, stream>>>(x, y, kx, ky, out);
}